// Round 7
// baseline (362.458 us; speedup 1.0000x reference)
//
#include <hip/hip_runtime.h>

#define NQ 14
#define NSTATE (1 << NQ)       // 16384 amplitudes
#define NL 3
#define NPASS (NL * 4)         // 4 fused 4-qubit sweeps per layer
#define BT 1024                // threads per block
#define NWAVES (BT / 64)

// Lazily-permuted simulation: CNOT rings folded into GF(2) index maps, and a
// global GF(2)-linear LDS layout sigma (amp p stored at address sigma(p)),
// chosen host-side so every pass's representative space projects rank-4 onto
// the bank-pair bits -> conflict-free b64 LDS access (R4 win: 5.57M -> 460K).
// R5/R6: layers 1-2 use Rot = P(omega) RY(theta) P(phi): diagonals collapse
// to wave-uniform 16-entry tables (D_pre/D_post), middle is a REAL RY stage
// (8 FMA-instr/pair vs 16). Layer 2's trailing diagonal is dropped (|amp|^2
// is phase-invariant). Gate data prefetched into regs BEFORE the pass
// barrier so the lgkm drain overlaps the barrier wait.
// R6 fix: a __syncthreads() AFTER the prologue — R5's ps=0 prefetch read the
// gate tables before the prologue writes were visible (NaN from poison).
struct PassP {
    unsigned short R[10];      // complement-basis images; R[0..3] bank pivots
    unsigned short cmb[16];    // XOR combos of the 4 pair-masks (addr space)
};
struct SimParams {
    PassP pass[NPASS];
    unsigned short ms[NQ];     // final Z_w selector masks (address space)
};

struct C2x2 { float2 m[2][2]; };

__device__ __forceinline__ float2 cmul(float2 a, float2 b) {
    return make_float2(a.x * b.x - a.y * b.y, a.x * b.y + a.y * b.x);
}
__device__ __forceinline__ float2 cmac(float2 acc, float2 a, float2 b) {
    acc.x = fmaf(a.x, b.x, fmaf(-a.y, b.y, acc.x));
    acc.y = fmaf(a.x, b.y, fmaf(a.y, b.x, acc.y));
    return acc;
}

// PennyLane Rot(phi,theta,omega) = RZ(omega) RY(theta) RZ(phi)
__device__ __forceinline__ C2x2 rot_gate(const float* qp) {
    float phi = qp[0], th = qp[1], om = qp[2];
    float ct, stt; __sincosf(0.5f * th, &stt, &ct);
    float sa, ca; __sincosf(0.5f * (phi + om), &sa, &ca);
    float sb, cb; __sincosf(0.5f * (phi - om), &sb, &cb);
    C2x2 G;
    G.m[0][0] = make_float2(ca * ct, -sa * ct);    // e^{-i(phi+om)/2} cos
    G.m[0][1] = make_float2(-cb * stt, -sb * stt); // -e^{+i(phi-om)/2} sin
    G.m[1][0] = make_float2(cb * stt, -sb * stt);  // e^{-i(phi-om)/2} sin
    G.m[1][1] = make_float2(ca * ct, sa * ct);     // e^{+i(phi+om)/2} cos
    return G;
}

// G := G * RX(ang)   (RX applied first to the state)
__device__ __forceinline__ C2x2 fuse_rx(C2x2 G, float ang) {
    float sh, ch; __sincosf(0.5f * ang, &sh, &ch);
    float2 c = make_float2(ch, 0.f), is = make_float2(0.f, -sh);
    C2x2 R;
    #pragma unroll
    for (int i = 0; i < 2; ++i) {
        R.m[i][0] = cmac(cmul(G.m[i][0], c), G.m[i][1], is);
        R.m[i][1] = cmac(cmul(G.m[i][1], c), G.m[i][0], is);
    }
    return R;
}

__global__ __launch_bounds__(BT) void qsim_kernel(
    const float* __restrict__ x, const float* __restrict__ qw,
    const float* __restrict__ wl, const float* __restrict__ bl,
    float* __restrict__ out, SimParams P)
{
    __shared__ float2 st[NSTATE];        // 128 KB state
    __shared__ float2 gbuf[16 * 4];      // layer-0: 16 gate slots (4 pass x 4 wire)
    __shared__ float2 cs[8 * 4];         // layers 1-2: (cos,sin)(theta/2) per pass-wire
    __shared__ float2 dpre[8][16];       // layers 1-2: combined RZ(phi) diagonal
    __shared__ float2 dpost[4][16];      // layer 1 only: combined RZ(omega) diagonal
    __shared__ float red[NWAVES];

    const int tid = threadIdx.x;
    const int b = blockIdx.x;

    for (int t = tid; t < NSTATE; t += BT) st[t] = make_float2(0.f, 0.f);
    if (tid == 0) st[0] = make_float2(1.f, 0.f);   // sigma(0) = 0

    // ---- prologue: gate tables (one-time) ----
    if (tid < 16) {
        // layer-0 fused Rot*RX general gates (incl. omega; RX depends on x[b])
        int p = tid >> 2, q = tid & 3;
        int nw = (p < 3) ? 4 : 2;
        C2x2 G;
        if (q < nw) {
            int w = p * 4 + q;
            G = rot_gate(qw + w * 3);
            G = fuse_rx(G, x[b * NQ + w]);
        } else {
            G.m[0][0] = make_float2(1.f, 0.f); G.m[0][1] = make_float2(0.f, 0.f);
            G.m[1][0] = make_float2(0.f, 0.f); G.m[1][1] = make_float2(1.f, 0.f);
        }
        gbuf[tid * 4 + 0] = G.m[0][0];
        gbuf[tid * 4 + 1] = G.m[0][1];
        gbuf[tid * 4 + 2] = G.m[1][0];
        gbuf[tid * 4 + 3] = G.m[1][1];
    } else if (tid < 48) {
        // RY(theta/2) cos/sin for layers 1-2
        int idx = tid - 16, cp = idx >> 2, q = idx & 3;
        int l = 1 + (cp >> 2), p = cp & 3;
        int nw = (p < 3) ? 4 : 2;
        float c = 1.f, s = 0.f;
        if (q < nw) {
            float th = qw[(l * NQ + p * 4 + q) * 3 + 1];
            __sincosf(0.5f * th, &s, &c);
        }
        cs[idx] = make_float2(c, s);
    } else if (tid < 176) {
        // D_pre[cp][i] = prod_q exp(+i phi_q/2 if bit_q(i) else -i phi_q/2)
        int idx = tid - 48, cp = idx >> 4, i = idx & 15;
        int l = 1 + (cp >> 2), p = cp & 3;
        int nw = (p < 3) ? 4 : 2;
        float ang = 0.f;
        for (int q = 0; q < nw; ++q) {
            float ph = 0.5f * qw[(l * NQ + p * 4 + q) * 3 + 0];
            ang += ((i >> q) & 1) ? ph : -ph;
        }
        float sn, cn; __sincosf(ang, &sn, &cn);
        dpre[cp][i] = make_float2(cn, sn);
    } else if (tid < 240) {
        // D_post for layer 1 (layer 2's is dropped: unobservable phase)
        int idx = tid - 176, cp = idx >> 4, i = idx & 15;
        int p = cp;
        int nw = (p < 3) ? 4 : 2;
        float ang = 0.f;
        for (int q = 0; q < nw; ++q) {
            float om = 0.5f * qw[(1 * NQ + p * 4 + q) * 3 + 2];
            ang += ((i >> q) & 1) ? om : -om;
        }
        float sn, cn; __sincosf(ang, &sn, &cn);
        dpost[cp][i] = make_float2(cn, sn);
    }

    __syncthreads();   // R6: tables + state init visible before any prefetch

    #pragma unroll 1
    for (int ps = 0; ps < NPASS; ++ps) {
        const int nw = ((ps & 3) < 3) ? 4 : 2;
        const bool l0 = (ps < 4);

        // address precompute (VALU, before the barrier)
        unsigned r = 0;
        #pragma unroll
        for (int j = 0; j < 10; ++j)
            r ^= ((tid >> j) & 1) ? (unsigned)P.pass[ps].R[j] : 0u;
        const unsigned rb = r << 3;          // byte offset

        unsigned c8[16];
        #pragma unroll
        for (int i = 0; i < 16; ++i)
            c8[i] = ((unsigned)P.pass[ps].cmb[i]) << 3;

        // gate prefetch into registers BEFORE the pass barrier (tables are
        // stable after the prologue barrier; lgkm drains during barrier wait)
        float2 g[16]; float2 csr[4]; float2 dp[16];
        if (l0) {
            #pragma unroll
            for (int i = 0; i < 16; ++i) g[i] = gbuf[ps * 16 + i];
        } else {
            #pragma unroll
            for (int q = 0; q < 4; ++q) csr[q] = cs[(ps - 4) * 4 + q];
            #pragma unroll
            for (int i = 0; i < 16; ++i) dp[i] = dpre[ps - 4][i];
        }

        if (ps > 0) __syncthreads();   // previous pass's writes visible

        char* sb = (char*)st;
        float2 a[16];
        #pragma unroll
        for (int i = 0; i < 16; ++i)
            a[i] = *(const float2*)(sb + (rb ^ c8[i]));

        if (l0) {
            // general 2x2 stages
            #pragma unroll
            for (int q = 0; q < 4; ++q) {
                if (q < nw) {
                    float2 g00 = g[q*4+0], g01 = g[q*4+1], g10 = g[q*4+2], g11 = g[q*4+3];
                    #pragma unroll
                    for (int i = 0; i < 16; ++i) {
                        if (!((i >> q) & 1)) {
                            const int i1 = i | (1 << q);
                            float2 a0 = a[i], a1 = a[i1];
                            float2 n0 = cmac(cmul(g00, a0), g01, a1);
                            float2 n1 = cmac(cmul(g10, a0), g11, a1);
                            a[i] = n0; a[i1] = n1;
                        }
                    }
                }
            }
        } else {
            // D_pre
            #pragma unroll
            for (int i = 0; i < 16; ++i) a[i] = cmul(a[i], dp[i]);
            // real RY stages
            #pragma unroll
            for (int q = 0; q < 4; ++q) {
                if (q < nw) {
                    const float c = csr[q].x, s = csr[q].y;
                    #pragma unroll
                    for (int i = 0; i < 16; ++i) {
                        if (!((i >> q) & 1)) {
                            const int i1 = i | (1 << q);
                            float2 a0 = a[i], a1 = a[i1];
                            float2 n0, n1;
                            n0.x = c * a0.x - s * a1.x;
                            n0.y = c * a0.y - s * a1.y;
                            n1.x = s * a0.x + c * a1.x;
                            n1.y = s * a0.y + c * a1.y;
                            a[i] = n0; a[i1] = n1;
                        }
                    }
                }
            }
            // D_post (layer 1 only; layer 2 phase unobservable)
            if (ps < 8) {
                #pragma unroll
                for (int i = 0; i < 16; ++i) a[i] = cmul(a[i], dpost[ps - 4][i]);
            }
        }

        #pragma unroll
        for (int i = 0; i < 16; ++i)
            *(float2*)(sb + (rb ^ c8[i])) = a[i];
    }

    __syncthreads();

    // ---- measurement: logit = sum_p |amp_p|^2 * ws(p) + bias (addr space) ----
    float A[16];
    #pragma unroll
    for (int k = 0; k < 16; ++k) A[k] = 0.f;
    #pragma unroll
    for (int w = 0; w < NQ; ++w) {
        const unsigned msw = (unsigned)P.ms[w];
        float v = wl[w];
        unsigned s0 = __popc((unsigned)tid & (msw & 1023u)) & 1u;
        float vs = s0 ? -v : v;
        const unsigned hk = msw >> 10;      // wave-uniform 4-bit pattern
        #pragma unroll
        for (int k = 0; k < 16; ++k) {
            bool neg = (__popc((unsigned)k & hk) & 1) != 0;
            A[k] += neg ? -vs : vs;
        }
    }

    float acc = 0.f;
    #pragma unroll
    for (int k = 0; k < 16; ++k) {
        float2 a = st[k * BT + tid];
        acc = fmaf(fmaf(a.x, a.x, a.y * a.y), A[k], acc);
    }

    #pragma unroll
    for (int off = 32; off > 0; off >>= 1) acc += __shfl_down(acc, off, 64);
    int lane = tid & 63, wid = tid >> 6;
    if (lane == 0) red[wid] = acc;
    __syncthreads();
    if (tid == 0) {
        float s = 0.f;
        #pragma unroll
        for (int i = 0; i < NWAVES; ++i) s += red[i];
        out[b] = s + bl[0];
    }
}

// ---- host-side GF(2) helpers ----
struct GF2Basis {
    unsigned piv[NQ];
    GF2Basis() { for (int i = 0; i < NQ; ++i) piv[i] = 0; }
    bool insert(unsigned v) {            // true iff rank increased
        for (int bb = NQ - 1; bb >= 0; --bb) {
            if (!((v >> bb) & 1)) continue;
            if (piv[bb]) v ^= piv[bb];
            else { piv[bb] = v; return true; }
        }
        return false;
    }
};

static inline int par16(unsigned v) { return __builtin_parity(v); }
static inline unsigned lcg_next(unsigned& s) { s = s * 1664525u + 1013904223u; return s >> 8; }

static unsigned gf_apply(const unsigned* C, unsigned v) {
    unsigned r = 0;
    while (v) { int j = __builtin_ctz(v); v &= v - 1; r ^= C[j]; }
    return r;
}

// C = columns of sigma; on success Ci = columns of sigma^{-1}
static bool gf_invert(const unsigned* C, unsigned* Ci) {
    unsigned rows[NQ], irows[NQ];
    for (int i = 0; i < NQ; ++i) {
        unsigned r = 0;
        for (int j = 0; j < NQ; ++j) r |= ((C[j] >> i) & 1u) << j;
        rows[i] = r; irows[i] = 1u << i;
    }
    for (int c = 0; c < NQ; ++c) {
        int p = -1;
        for (int r = c; r < NQ; ++r) if ((rows[r] >> c) & 1u) { p = r; break; }
        if (p < 0) return false;
        unsigned t = rows[p]; rows[p] = rows[c]; rows[c] = t;
        t = irows[p]; irows[p] = irows[c]; irows[c] = t;
        for (int r = 0; r < NQ; ++r)
            if (r != c && ((rows[r] >> c) & 1u)) { rows[r] ^= rows[c]; irows[r] ^= irows[c]; }
    }
    for (int j = 0; j < NQ; ++j) {
        unsigned col = 0;
        for (int i = 0; i < NQ; ++i) col |= ((irows[i] >> j) & 1u) << i;
        Ci[j] = col;
    }
    return true;
}

extern "C" void kernel_launch(void* const* d_in, const int* in_sizes, int n_in,
                              void* d_out, int out_size, void* d_ws, size_t ws_size,
                              hipStream_t stream) {
    const float* x  = (const float*)d_in[0];   // (B, 14)
    const float* qw = (const float*)d_in[1];   // (3, 14, 3)
    const float* wl = (const float*)d_in[2];   // (1, 14)
    const float* bl = (const float*)d_in[3];   // (1,)
    float* out = (float*)d_out;                // (B, 1)

    const int B = in_sizes[0] / NQ;

    // ---- build passes in INDEX space (lazy-CNOT GF(2) bookkeeping) ----
    // s[w] = selector row of Q, m[w] = column of Q^-1; par(s_i & m_j)=delta_ij.
    struct Raw { unsigned rv[10], cmb[16]; } raw[NPASS];
    unsigned s[NQ], m[NQ], msIdx[NQ];
    for (int w = 0; w < NQ; ++w) s[w] = m[w] = 1u << (NQ - 1 - w); // wire 0 = MSB

    int ps = 0;
    for (int l = 0; l < NL; ++l) {
        for (int g0 = 0; g0 < NQ; g0 += 4) {
            int nw = (NQ - g0) < 4 ? (NQ - g0) : 4;
            unsigned mm[4], ss[4];
            GF2Basis gf;
            for (int i = 0; i < nw; ++i) { mm[i] = m[g0 + i]; ss[i] = s[g0 + i]; gf.insert(mm[i]); }
            // pad to 4 independent masks; normalize pads so they don't flip
            // the real wires' logical bits
            for (int i = nw; i < 4; ++i) {
                unsigned cand = 0;
                for (int t = 0; t < NQ; ++t)
                    if (gf.insert(1u << t)) { cand = 1u << t; break; }
                for (int j = 0; j < nw; ++j)
                    if (par16(cand & ss[j])) cand ^= mm[j];
                mm[i] = cand; ss[i] = 0;
            }
            // complement basis (10 vecs), normalized to zero logical bits
            int nR = 0;
            for (int t = 0; t < NQ && nR < 10; ++t) {
                if (gf.insert(1u << t)) {
                    unsigned v = 1u << t;
                    for (int j = 0; j < nw; ++j)
                        if (par16(v & ss[j])) v ^= mm[j];
                    raw[ps].rv[nR++] = v;
                }
            }
            for (int idx = 0; idx < 16; ++idx) {
                unsigned c = 0;
                for (int q = 0; q < 4; ++q) if ((idx >> q) & 1) c ^= mm[q];
                raw[ps].cmb[idx] = c;
            }
            ++ps;
        }
        int r = (l % (NQ - 1)) + 1;        // PennyLane ranges: 1,2,3
        for (int w = 0; w < NQ; ++w) {     // CNOT ring: control w, target (w+r)%NQ
            int c = w, t = (w + r) % NQ;
            s[t] ^= s[c];
            m[c] ^= m[t];
        }
    }
    for (int w = 0; w < NQ; ++w) msIdx[w] = s[w];

    // ---- choose layout sigma: every pass's rep space must project with
    // rank 4 onto the bank-pair bits (addr mod 16) ----
    unsigned Cm[NQ], Ci[NQ];
    unsigned seed = 0x9E3779B9u;
    bool found = false;
    for (int tries = 0; tries < 5000 && !found; ++tries) {
        for (int j = 0; j < NQ; ++j) Cm[j] = lcg_next(seed) & (NSTATE - 1);
        if (!gf_invert(Cm, Ci)) continue;
        found = true;
        for (int p = 0; p < NPASS && found; ++p) {
            unsigned piv[4] = {0, 0, 0, 0}; int np = 0;
            for (int i = 0; i < 10; ++i) {
                unsigned w2 = gf_apply(Cm, raw[p].rv[i]);
                for (int bb = 0; bb < 4; ++bb)
                    if (((w2 >> bb) & 1u) && piv[bb]) w2 ^= piv[bb];
                if ((w2 & 15u) && np < 4) { piv[__builtin_ctz(w2 & 15u)] = w2; ++np; }
            }
            if (np < 4) found = false;
        }
    }
    if (!found) {  // fallback: identity layout (correct, just slower)
        for (int j = 0; j < NQ; ++j) Cm[j] = 1u << j;
        gf_invert(Cm, Ci);
    }

    // ---- emit device params in ADDRESS space ----
    SimParams P;
    for (int p = 0; p < NPASS; ++p) {
        unsigned u[10];
        for (int i = 0; i < 10; ++i) u[i] = gf_apply(Cm, raw[p].rv[i]);
        // order: 4 bank-pivot vectors first (they cover lane bits 0..3)
        unsigned piv[4] = {0, 0, 0, 0};
        int ord[10], np = 0, rest[10], nrest = 0;
        for (int i = 0; i < 10; ++i) {
            unsigned w2 = u[i];
            for (int bb = 0; bb < 4; ++bb)
                if (((w2 >> bb) & 1u) && piv[bb]) w2 ^= piv[bb];
            if ((w2 & 15u) && np < 4) { piv[__builtin_ctz(w2 & 15u)] = w2; ord[np++] = i; }
            else rest[nrest++] = i;
        }
        int kk = 0;
        for (int i = 0; i < np; ++i) P.pass[p].R[kk++] = (unsigned short)u[ord[i]];
        for (int i = 0; i < nrest; ++i) P.pass[p].R[kk++] = (unsigned short)u[rest[i]];
        for (int idx = 0; idx < 16; ++idx)
            P.pass[p].cmb[idx] = (unsigned short)gf_apply(Cm, raw[p].cmb[idx]);
    }
    // measurement masks: par(sigma^{-1}(t) & ms) = par(t & sigma^{-T} ms)
    for (int w = 0; w < NQ; ++w) {
        unsigned msp = 0;
        for (int i = 0; i < NQ; ++i)
            msp |= (unsigned)(par16(Ci[i] & msIdx[w]) & 1) << i;
        P.ms[w] = (unsigned short)msp;
    }

    qsim_kernel<<<dim3(B), dim3(BT), 0, stream>>>(x, qw, wl, bl, out, P);
}

// Round 8
// 135.600 us; speedup vs baseline: 2.6730x; 2.6730x over previous
//
#include <hip/hip_runtime.h>

#define NQ 14
#define NSTATE (1 << NQ)       // 16384 amplitudes
#define NL 3
#define NPASS (NL * 4)         // 4 fused 4-qubit sweeps per layer
#define BT 1024                // threads per block
#define NWAVES (BT / 64)

// Lazily-permuted simulation: CNOT rings folded into GF(2) index maps, and a
// global GF(2)-linear LDS layout sigma (amp p stored at address sigma(p)),
// chosen host-side so every pass's representative space projects rank-4 onto
// the bank-pair bits -> conflict-free b64 LDS access (R4: 5.57M -> 460K).
// Layers 1-2 use Rot = P(omega) RY(theta) P(phi): diagonals collapse to
// wave-uniform 16-entry tables (D_pre/D_post), middle is a REAL RY stage
// (8 FMA-instr/pair vs 16). Layer 2's trailing diagonal is dropped (|amp|^2
// is phase-invariant). R7: gates are read from LDS at USE time (broadcast) —
// R6's pre-barrier register prefetch spilled to scratch (880 MB HBM/dispatch);
// __launch_bounds__(BT,4) raises the VGPR cap to the 4-waves/SIMD budget.
struct PassP {
    unsigned short R[10];      // complement-basis images; R[0..3] bank pivots
    unsigned short cmb[16];    // XOR combos of the 4 pair-masks (addr space)
};
struct SimParams {
    PassP pass[NPASS];
    unsigned short ms[NQ];     // final Z_w selector masks (address space)
};

struct C2x2 { float2 m[2][2]; };

__device__ __forceinline__ float2 cmul(float2 a, float2 b) {
    return make_float2(a.x * b.x - a.y * b.y, a.x * b.y + a.y * b.x);
}
__device__ __forceinline__ float2 cmac(float2 acc, float2 a, float2 b) {
    acc.x = fmaf(a.x, b.x, fmaf(-a.y, b.y, acc.x));
    acc.y = fmaf(a.x, b.y, fmaf(a.y, b.x, acc.y));
    return acc;
}

// PennyLane Rot(phi,theta,omega) = RZ(omega) RY(theta) RZ(phi)
__device__ __forceinline__ C2x2 rot_gate(const float* qp) {
    float phi = qp[0], th = qp[1], om = qp[2];
    float ct, stt; __sincosf(0.5f * th, &stt, &ct);
    float sa, ca; __sincosf(0.5f * (phi + om), &sa, &ca);
    float sb, cb; __sincosf(0.5f * (phi - om), &sb, &cb);
    C2x2 G;
    G.m[0][0] = make_float2(ca * ct, -sa * ct);    // e^{-i(phi+om)/2} cos
    G.m[0][1] = make_float2(-cb * stt, -sb * stt); // -e^{+i(phi-om)/2} sin
    G.m[1][0] = make_float2(cb * stt, -sb * stt);  // e^{-i(phi-om)/2} sin
    G.m[1][1] = make_float2(ca * ct, sa * ct);     // e^{+i(phi+om)/2} cos
    return G;
}

// G := G * RX(ang)   (RX applied first to the state)
__device__ __forceinline__ C2x2 fuse_rx(C2x2 G, float ang) {
    float sh, ch; __sincosf(0.5f * ang, &sh, &ch);
    float2 c = make_float2(ch, 0.f), is = make_float2(0.f, -sh);
    C2x2 R;
    #pragma unroll
    for (int i = 0; i < 2; ++i) {
        R.m[i][0] = cmac(cmul(G.m[i][0], c), G.m[i][1], is);
        R.m[i][1] = cmac(cmul(G.m[i][1], c), G.m[i][0], is);
    }
    return R;
}

__global__ __launch_bounds__(BT, 4) void qsim_kernel(
    const float* __restrict__ x, const float* __restrict__ qw,
    const float* __restrict__ wl, const float* __restrict__ bl,
    float* __restrict__ out, SimParams P)
{
    __shared__ float2 st[NSTATE];        // 128 KB state
    __shared__ float2 gbuf[16 * 4];      // layer-0: 16 gate slots (4 pass x 4 wire)
    __shared__ float2 cs[8 * 4];         // layers 1-2: (cos,sin)(theta/2) per pass-wire
    __shared__ float2 dpre[8][16];       // layers 1-2: combined RZ(phi) diagonal
    __shared__ float2 dpost[4][16];      // layer 1 only: combined RZ(omega) diagonal
    __shared__ float red[NWAVES];

    const int tid = threadIdx.x;
    const int b = blockIdx.x;

    for (int t = tid; t < NSTATE; t += BT) st[t] = make_float2(0.f, 0.f);
    if (tid == 0) st[0] = make_float2(1.f, 0.f);   // sigma(0) = 0

    // ---- prologue: gate tables (one-time) ----
    if (tid < 16) {
        // layer-0 fused Rot*RX general gates (incl. omega; RX depends on x[b])
        int p = tid >> 2, q = tid & 3;
        int nw = (p < 3) ? 4 : 2;
        C2x2 G;
        if (q < nw) {
            int w = p * 4 + q;
            G = rot_gate(qw + w * 3);
            G = fuse_rx(G, x[b * NQ + w]);
        } else {
            G.m[0][0] = make_float2(1.f, 0.f); G.m[0][1] = make_float2(0.f, 0.f);
            G.m[1][0] = make_float2(0.f, 0.f); G.m[1][1] = make_float2(1.f, 0.f);
        }
        gbuf[tid * 4 + 0] = G.m[0][0];
        gbuf[tid * 4 + 1] = G.m[0][1];
        gbuf[tid * 4 + 2] = G.m[1][0];
        gbuf[tid * 4 + 3] = G.m[1][1];
    } else if (tid < 48) {
        // RY(theta/2) cos/sin for layers 1-2
        int idx = tid - 16, cp = idx >> 2, q = idx & 3;
        int l = 1 + (cp >> 2), p = cp & 3;
        int nw = (p < 3) ? 4 : 2;
        float c = 1.f, s = 0.f;
        if (q < nw) {
            float th = qw[(l * NQ + p * 4 + q) * 3 + 1];
            __sincosf(0.5f * th, &s, &c);
        }
        cs[idx] = make_float2(c, s);
    } else if (tid < 176) {
        // D_pre[cp][i] = prod_q exp(+i phi_q/2 if bit_q(i) else -i phi_q/2)
        int idx = tid - 48, cp = idx >> 4, i = idx & 15;
        int l = 1 + (cp >> 2), p = cp & 3;
        int nw = (p < 3) ? 4 : 2;
        float ang = 0.f;
        for (int q = 0; q < nw; ++q) {
            float ph = 0.5f * qw[(l * NQ + p * 4 + q) * 3 + 0];
            ang += ((i >> q) & 1) ? ph : -ph;
        }
        float sn, cn; __sincosf(ang, &sn, &cn);
        dpre[cp][i] = make_float2(cn, sn);
    } else if (tid < 240) {
        // D_post for layer 1 (layer 2's is dropped: unobservable phase)
        int idx = tid - 176, cp = idx >> 4, i = idx & 15;
        int p = cp;
        int nw = (p < 3) ? 4 : 2;
        float ang = 0.f;
        for (int q = 0; q < nw; ++q) {
            float om = 0.5f * qw[(1 * NQ + p * 4 + q) * 3 + 2];
            ang += ((i >> q) & 1) ? om : -om;
        }
        float sn, cn; __sincosf(ang, &sn, &cn);
        dpost[cp][i] = make_float2(cn, sn);
    }

    __syncthreads();   // tables + state init visible before first pass

    #pragma unroll 1
    for (int ps = 0; ps < NPASS; ++ps) {
        const int nw = ((ps & 3) < 3) ? 4 : 2;
        const bool l0 = (ps < 4);

        // address precompute (VALU, overlaps barrier wait)
        unsigned r = 0;
        #pragma unroll
        for (int j = 0; j < 10; ++j)
            r ^= ((tid >> j) & 1) ? (unsigned)P.pass[ps].R[j] : 0u;
        const unsigned rb = r << 3;          // byte offset

        unsigned c8[16];
        #pragma unroll
        for (int i = 0; i < 16; ++i)
            c8[i] = ((unsigned)P.pass[ps].cmb[i]) << 3;

        if (ps > 0) __syncthreads();   // previous pass's writes visible

        char* sb = (char*)st;
        float2 a[16];
        #pragma unroll
        for (int i = 0; i < 16; ++i)
            a[i] = *(const float2*)(sb + (rb ^ c8[i]));

        if (l0) {
            // general 2x2 stages; gates broadcast-read from LDS at use
            #pragma unroll
            for (int q = 0; q < 4; ++q) {
                if (q < nw) {
                    const int gi = (ps * 4 + q) * 4;
                    float2 g00 = gbuf[gi + 0], g01 = gbuf[gi + 1];
                    float2 g10 = gbuf[gi + 2], g11 = gbuf[gi + 3];
                    #pragma unroll
                    for (int i = 0; i < 16; ++i) {
                        if (!((i >> q) & 1)) {
                            const int i1 = i | (1 << q);
                            float2 a0 = a[i], a1 = a[i1];
                            float2 n0 = cmac(cmul(g00, a0), g01, a1);
                            float2 n1 = cmac(cmul(g10, a0), g11, a1);
                            a[i] = n0; a[i1] = n1;
                        }
                    }
                }
            }
        } else {
            const int cp = ps - 4;
            // D_pre (broadcast LDS reads)
            #pragma unroll
            for (int i = 0; i < 16; ++i) a[i] = cmul(a[i], dpre[cp][i]);
            // real RY stages
            #pragma unroll
            for (int q = 0; q < 4; ++q) {
                if (q < nw) {
                    const float2 csq = cs[cp * 4 + q];
                    const float c = csq.x, s = csq.y;
                    #pragma unroll
                    for (int i = 0; i < 16; ++i) {
                        if (!((i >> q) & 1)) {
                            const int i1 = i | (1 << q);
                            float2 a0 = a[i], a1 = a[i1];
                            float2 n0, n1;
                            n0.x = c * a0.x - s * a1.x;
                            n0.y = c * a0.y - s * a1.y;
                            n1.x = s * a0.x + c * a1.x;
                            n1.y = s * a0.y + c * a1.y;
                            a[i] = n0; a[i1] = n1;
                        }
                    }
                }
            }
            // D_post (layer 1 only; layer 2 phase unobservable)
            if (ps < 8) {
                #pragma unroll
                for (int i = 0; i < 16; ++i) a[i] = cmul(a[i], dpost[cp][i]);
            }
        }

        #pragma unroll
        for (int i = 0; i < 16; ++i)
            *(float2*)(sb + (rb ^ c8[i])) = a[i];
    }

    __syncthreads();

    // ---- measurement: logit = sum_p |amp_p|^2 * ws(p) + bias (addr space) ----
    float A[16];
    #pragma unroll
    for (int k = 0; k < 16; ++k) A[k] = 0.f;
    #pragma unroll
    for (int w = 0; w < NQ; ++w) {
        const unsigned msw = (unsigned)P.ms[w];
        float v = wl[w];
        unsigned s0 = __popc((unsigned)tid & (msw & 1023u)) & 1u;
        float vs = s0 ? -v : v;
        const unsigned hk = msw >> 10;      // wave-uniform 4-bit pattern
        #pragma unroll
        for (int k = 0; k < 16; ++k) {
            bool neg = (__popc((unsigned)k & hk) & 1) != 0;
            A[k] += neg ? -vs : vs;
        }
    }

    float acc = 0.f;
    #pragma unroll
    for (int k = 0; k < 16; ++k) {
        float2 a = st[k * BT + tid];
        acc = fmaf(fmaf(a.x, a.x, a.y * a.y), A[k], acc);
    }

    #pragma unroll
    for (int off = 32; off > 0; off >>= 1) acc += __shfl_down(acc, off, 64);
    int lane = tid & 63, wid = tid >> 6;
    if (lane == 0) red[wid] = acc;
    __syncthreads();
    if (tid == 0) {
        float s = 0.f;
        #pragma unroll
        for (int i = 0; i < NWAVES; ++i) s += red[i];
        out[b] = s + bl[0];
    }
}

// ---- host-side GF(2) helpers ----
struct GF2Basis {
    unsigned piv[NQ];
    GF2Basis() { for (int i = 0; i < NQ; ++i) piv[i] = 0; }
    bool insert(unsigned v) {            // true iff rank increased
        for (int bb = NQ - 1; bb >= 0; --bb) {
            if (!((v >> bb) & 1)) continue;
            if (piv[bb]) v ^= piv[bb];
            else { piv[bb] = v; return true; }
        }
        return false;
    }
};

static inline int par16(unsigned v) { return __builtin_parity(v); }
static inline unsigned lcg_next(unsigned& s) { s = s * 1664525u + 1013904223u; return s >> 8; }

static unsigned gf_apply(const unsigned* C, unsigned v) {
    unsigned r = 0;
    while (v) { int j = __builtin_ctz(v); v &= v - 1; r ^= C[j]; }
    return r;
}

// C = columns of sigma; on success Ci = columns of sigma^{-1}
static bool gf_invert(const unsigned* C, unsigned* Ci) {
    unsigned rows[NQ], irows[NQ];
    for (int i = 0; i < NQ; ++i) {
        unsigned r = 0;
        for (int j = 0; j < NQ; ++j) r |= ((C[j] >> i) & 1u) << j;
        rows[i] = r; irows[i] = 1u << i;
    }
    for (int c = 0; c < NQ; ++c) {
        int p = -1;
        for (int r = c; r < NQ; ++r) if ((rows[r] >> c) & 1u) { p = r; break; }
        if (p < 0) return false;
        unsigned t = rows[p]; rows[p] = rows[c]; rows[c] = t;
        t = irows[p]; irows[p] = irows[c]; irows[c] = t;
        for (int r = 0; r < NQ; ++r)
            if (r != c && ((rows[r] >> c) & 1u)) { rows[r] ^= rows[c]; irows[r] ^= irows[c]; }
    }
    for (int j = 0; j < NQ; ++j) {
        unsigned col = 0;
        for (int i = 0; i < NQ; ++i) col |= ((irows[i] >> j) & 1u) << i;
        Ci[j] = col;
    }
    return true;
}

extern "C" void kernel_launch(void* const* d_in, const int* in_sizes, int n_in,
                              void* d_out, int out_size, void* d_ws, size_t ws_size,
                              hipStream_t stream) {
    const float* x  = (const float*)d_in[0];   // (B, 14)
    const float* qw = (const float*)d_in[1];   // (3, 14, 3)
    const float* wl = (const float*)d_in[2];   // (1, 14)
    const float* bl = (const float*)d_in[3];   // (1,)
    float* out = (float*)d_out;                // (B, 1)

    const int B = in_sizes[0] / NQ;

    // ---- build passes in INDEX space (lazy-CNOT GF(2) bookkeeping) ----
    // s[w] = selector row of Q, m[w] = column of Q^-1; par(s_i & m_j)=delta_ij.
    struct Raw { unsigned rv[10], cmb[16]; } raw[NPASS];
    unsigned s[NQ], m[NQ], msIdx[NQ];
    for (int w = 0; w < NQ; ++w) s[w] = m[w] = 1u << (NQ - 1 - w); // wire 0 = MSB

    int ps = 0;
    for (int l = 0; l < NL; ++l) {
        for (int g0 = 0; g0 < NQ; g0 += 4) {
            int nw = (NQ - g0) < 4 ? (NQ - g0) : 4;
            unsigned mm[4], ss[4];
            GF2Basis gf;
            for (int i = 0; i < nw; ++i) { mm[i] = m[g0 + i]; ss[i] = s[g0 + i]; gf.insert(mm[i]); }
            // pad to 4 independent masks; normalize pads so they don't flip
            // the real wires' logical bits
            for (int i = nw; i < 4; ++i) {
                unsigned cand = 0;
                for (int t = 0; t < NQ; ++t)
                    if (gf.insert(1u << t)) { cand = 1u << t; break; }
                for (int j = 0; j < nw; ++j)
                    if (par16(cand & ss[j])) cand ^= mm[j];
                mm[i] = cand; ss[i] = 0;
            }
            // complement basis (10 vecs), normalized to zero logical bits
            int nR = 0;
            for (int t = 0; t < NQ && nR < 10; ++t) {
                if (gf.insert(1u << t)) {
                    unsigned v = 1u << t;
                    for (int j = 0; j < nw; ++j)
                        if (par16(v & ss[j])) v ^= mm[j];
                    raw[ps].rv[nR++] = v;
                }
            }
            for (int idx = 0; idx < 16; ++idx) {
                unsigned c = 0;
                for (int q = 0; q < 4; ++q) if ((idx >> q) & 1) c ^= mm[q];
                raw[ps].cmb[idx] = c;
            }
            ++ps;
        }
        int r = (l % (NQ - 1)) + 1;        // PennyLane ranges: 1,2,3
        for (int w = 0; w < NQ; ++w) {     // CNOT ring: control w, target (w+r)%NQ
            int c = w, t = (w + r) % NQ;
            s[t] ^= s[c];
            m[c] ^= m[t];
        }
    }
    for (int w = 0; w < NQ; ++w) msIdx[w] = s[w];

    // ---- choose layout sigma: every pass's rep space must project with
    // rank 4 onto the bank-pair bits (addr mod 16) ----
    unsigned Cm[NQ], Ci[NQ];
    unsigned seed = 0x9E3779B9u;
    bool found = false;
    for (int tries = 0; tries < 5000 && !found; ++tries) {
        for (int j = 0; j < NQ; ++j) Cm[j] = lcg_next(seed) & (NSTATE - 1);
        if (!gf_invert(Cm, Ci)) continue;
        found = true;
        for (int p = 0; p < NPASS && found; ++p) {
            unsigned piv[4] = {0, 0, 0, 0}; int np = 0;
            for (int i = 0; i < 10; ++i) {
                unsigned w2 = gf_apply(Cm, raw[p].rv[i]);
                for (int bb = 0; bb < 4; ++bb)
                    if (((w2 >> bb) & 1u) && piv[bb]) w2 ^= piv[bb];
                if ((w2 & 15u) && np < 4) { piv[__builtin_ctz(w2 & 15u)] = w2; ++np; }
            }
            if (np < 4) found = false;
        }
    }
    if (!found) {  // fallback: identity layout (correct, just slower)
        for (int j = 0; j < NQ; ++j) Cm[j] = 1u << j;
        gf_invert(Cm, Ci);
    }

    // ---- emit device params in ADDRESS space ----
    SimParams P;
    for (int p = 0; p < NPASS; ++p) {
        unsigned u[10];
        for (int i = 0; i < 10; ++i) u[i] = gf_apply(Cm, raw[p].rv[i]);
        // order: 4 bank-pivot vectors first (they cover lane bits 0..3)
        unsigned piv[4] = {0, 0, 0, 0};
        int ord[10], np = 0, rest[10], nrest = 0;
        for (int i = 0; i < 10; ++i) {
            unsigned w2 = u[i];
            for (int bb = 0; bb < 4; ++bb)
                if (((w2 >> bb) & 1u) && piv[bb]) w2 ^= piv[bb];
            if ((w2 & 15u) && np < 4) { piv[__builtin_ctz(w2 & 15u)] = w2; ord[np++] = i; }
            else rest[nrest++] = i;
        }
        int kk = 0;
        for (int i = 0; i < np; ++i) P.pass[p].R[kk++] = (unsigned short)u[ord[i]];
        for (int i = 0; i < nrest; ++i) P.pass[p].R[kk++] = (unsigned short)u[rest[i]];
        for (int idx = 0; idx < 16; ++idx)
            P.pass[p].cmb[idx] = (unsigned short)gf_apply(Cm, raw[p].cmb[idx]);
    }
    // measurement masks: par(sigma^{-1}(t) & ms) = par(t & sigma^{-T} ms)
    for (int w = 0; w < NQ; ++w) {
        unsigned msp = 0;
        for (int i = 0; i < NQ; ++i)
            msp |= (unsigned)(par16(Ci[i] & msIdx[w]) & 1) << i;
        P.ms[w] = (unsigned short)msp;
    }

    qsim_kernel<<<dim3(B), dim3(BT), 0, stream>>>(x, qw, wl, bl, out, P);
}

// Round 9
// 131.005 us; speedup vs baseline: 2.7667x; 1.0351x over previous
//
#include <hip/hip_runtime.h>

#define NQ 14
#define NSTATE (1 << NQ)       // 16384 amplitudes
#define NL 3
#define NPASS (NL * 4)         // 4 fused 4-qubit sweeps per layer
#define BT 1024                // threads per block
#define NWAVES (BT / 64)

// ws layout (float2 units): [0,32) cs; [32,160) dpre[8][16]; [160,224) dpost[4][16]
#define WS_CS 0
#define WS_DPRE 32
#define WS_DPOST 160

// Lazily-permuted simulation: CNOT rings folded into GF(2) index maps, and a
// global GF(2)-linear LDS layout sigma (amp p stored at address sigma(p)),
// chosen host-side so every pass's representative space projects rank-4 onto
// the bank-pair bits -> conflict-free b64 LDS access (R4: 5.57M -> 460K).
// Layers 1-2 use Rot = P(omega) RY(theta) P(phi): diagonals collapse to
// block-uniform 16-entry tables, middle is a REAL RY stage. Layer 2's
// trailing diagonal dropped (|amp|^2 phase-invariant).
// R8: diagonal tables are batch-independent -> computed once by a 1-block
// prep kernel into d_ws; main kernel reads them via UNIFORM-address global
// loads (s_load -> SGPRs, zero VGPR pressure). R6/R7's spill came from
// materializing these 16 float2 in VGPRs on top of a[16]+c8[16].
struct PassP {
    unsigned short R[10];      // complement-basis images; R[0..3] bank pivots
    unsigned short cmb[16];    // XOR combos of the 4 pair-masks (addr space)
};
struct SimParams {
    PassP pass[NPASS];
    unsigned short ms[NQ];     // final Z_w selector masks (address space)
};

struct C2x2 { float2 m[2][2]; };

__device__ __forceinline__ float2 cmul(float2 a, float2 b) {
    return make_float2(a.x * b.x - a.y * b.y, a.x * b.y + a.y * b.x);
}
__device__ __forceinline__ float2 cmac(float2 acc, float2 a, float2 b) {
    acc.x = fmaf(a.x, b.x, fmaf(-a.y, b.y, acc.x));
    acc.y = fmaf(a.x, b.y, fmaf(a.y, b.x, acc.y));
    return acc;
}

// PennyLane Rot(phi,theta,omega) = RZ(omega) RY(theta) RZ(phi)
__device__ __forceinline__ C2x2 rot_gate(const float* qp) {
    float phi = qp[0], th = qp[1], om = qp[2];
    float ct, stt; __sincosf(0.5f * th, &stt, &ct);
    float sa, ca; __sincosf(0.5f * (phi + om), &sa, &ca);
    float sb, cb; __sincosf(0.5f * (phi - om), &sb, &cb);
    C2x2 G;
    G.m[0][0] = make_float2(ca * ct, -sa * ct);    // e^{-i(phi+om)/2} cos
    G.m[0][1] = make_float2(-cb * stt, -sb * stt); // -e^{+i(phi-om)/2} sin
    G.m[1][0] = make_float2(cb * stt, -sb * stt);  // e^{-i(phi-om)/2} sin
    G.m[1][1] = make_float2(ca * ct, sa * ct);     // e^{+i(phi+om)/2} cos
    return G;
}

// G := G * RX(ang)   (RX applied first to the state)
__device__ __forceinline__ C2x2 fuse_rx(C2x2 G, float ang) {
    float sh, ch; __sincosf(0.5f * ang, &sh, &ch);
    float2 c = make_float2(ch, 0.f), is = make_float2(0.f, -sh);
    C2x2 R;
    #pragma unroll
    for (int i = 0; i < 2; ++i) {
        R.m[i][0] = cmac(cmul(G.m[i][0], c), G.m[i][1], is);
        R.m[i][1] = cmac(cmul(G.m[i][1], c), G.m[i][0], is);
    }
    return R;
}

// ---- prep: batch-independent diagonal/RY tables -> d_ws ----
__global__ __launch_bounds__(256) void prep_kernel(
    const float* __restrict__ qw, float2* __restrict__ ws)
{
    int tid = threadIdx.x;
    if (tid < 32) {
        // cs[cp*4+q] = (cos,sin)(theta/2), layers 1-2
        int cp = tid >> 2, q = tid & 3;
        int l = 1 + (cp >> 2), p = cp & 3;
        int nw = (p < 3) ? 4 : 2;
        float c = 1.f, s = 0.f;
        if (q < nw) __sincosf(0.5f * qw[(l * NQ + p * 4 + q) * 3 + 1], &s, &c);
        ws[WS_CS + tid] = make_float2(c, s);
    } else if (tid < 160) {
        // dpre[cp][i] = prod_q exp(+i phi_q/2 if bit_q(i) else -)
        int idx = tid - 32, cp = idx >> 4, i = idx & 15;
        int l = 1 + (cp >> 2), p = cp & 3;
        int nw = (p < 3) ? 4 : 2;
        float ang = 0.f;
        for (int q = 0; q < nw; ++q) {
            float ph = 0.5f * qw[(l * NQ + p * 4 + q) * 3 + 0];
            ang += ((i >> q) & 1) ? ph : -ph;
        }
        float sn, cn; __sincosf(ang, &sn, &cn);
        ws[WS_DPRE + idx] = make_float2(cn, sn);
    } else if (tid < 224) {
        // dpost[cp][i], layer 1 only (layer 2's dropped: unobservable phase)
        int idx = tid - 160, cp = idx >> 4, i = idx & 15;
        int nw = (cp < 3) ? 4 : 2;
        float ang = 0.f;
        for (int q = 0; q < nw; ++q) {
            float om = 0.5f * qw[(1 * NQ + cp * 4 + q) * 3 + 2];
            ang += ((i >> q) & 1) ? om : -om;
        }
        float sn, cn; __sincosf(ang, &sn, &cn);
        ws[WS_DPOST + idx] = make_float2(cn, sn);
    }
}

__global__ __launch_bounds__(BT) void qsim_kernel(
    const float* __restrict__ x, const float* __restrict__ qw,
    const float* __restrict__ wl, const float* __restrict__ bl,
    float* __restrict__ out, const float2* __restrict__ gtab, SimParams P)
{
    __shared__ float2 st[NSTATE];        // 128 KB state
    __shared__ float2 gbuf[16 * 4];      // layer-0: 16 gate slots (x-dependent)
    __shared__ float red[NWAVES];

    const int tid = threadIdx.x;
    const int b = blockIdx.x;

    for (int t = tid; t < NSTATE; t += BT) st[t] = make_float2(0.f, 0.f);
    if (tid == 0) st[0] = make_float2(1.f, 0.f);   // sigma(0) = 0

    // prologue: layer-0 fused Rot*RX gates (batch-dependent)
    if (tid < 16) {
        int p = tid >> 2, q = tid & 3;
        int nw = (p < 3) ? 4 : 2;
        C2x2 G;
        if (q < nw) {
            int w = p * 4 + q;
            G = rot_gate(qw + w * 3);
            G = fuse_rx(G, x[b * NQ + w]);
        } else {
            G.m[0][0] = make_float2(1.f, 0.f); G.m[0][1] = make_float2(0.f, 0.f);
            G.m[1][0] = make_float2(0.f, 0.f); G.m[1][1] = make_float2(1.f, 0.f);
        }
        gbuf[tid * 4 + 0] = G.m[0][0];
        gbuf[tid * 4 + 1] = G.m[0][1];
        gbuf[tid * 4 + 2] = G.m[1][0];
        gbuf[tid * 4 + 3] = G.m[1][1];
    }

    __syncthreads();   // tables + state init visible before first pass

    #pragma unroll 1
    for (int ps = 0; ps < NPASS; ++ps) {
        const int nw = ((ps & 3) < 3) ? 4 : 2;
        const bool l0 = (ps < 4);

        // address precompute (VALU, overlaps barrier wait)
        unsigned r = 0;
        #pragma unroll
        for (int j = 0; j < 10; ++j)
            r ^= ((tid >> j) & 1) ? (unsigned)P.pass[ps].R[j] : 0u;
        const unsigned rb = r << 3;          // byte offset

        unsigned c8[16];
        #pragma unroll
        for (int i = 0; i < 16; ++i)
            c8[i] = ((unsigned)P.pass[ps].cmb[i]) << 3;

        if (ps > 0) __syncthreads();   // previous pass's writes visible

        char* sb = (char*)st;
        float2 a[16];
        #pragma unroll
        for (int i = 0; i < 16; ++i)
            a[i] = *(const float2*)(sb + (rb ^ c8[i]));

        if (l0) {
            // general 2x2 stages; gates broadcast-read from LDS at use
            #pragma unroll
            for (int q = 0; q < 4; ++q) {
                if (q < nw) {
                    const int gi = (ps * 4 + q) * 4;
                    float2 g00 = gbuf[gi + 0], g01 = gbuf[gi + 1];
                    float2 g10 = gbuf[gi + 2], g11 = gbuf[gi + 3];
                    #pragma unroll
                    for (int i = 0; i < 16; ++i) {
                        if (!((i >> q) & 1)) {
                            const int i1 = i | (1 << q);
                            float2 a0 = a[i], a1 = a[i1];
                            float2 n0 = cmac(cmul(g00, a0), g01, a1);
                            float2 n1 = cmac(cmul(g10, a0), g11, a1);
                            a[i] = n0; a[i1] = n1;
                        }
                    }
                }
            }
        } else {
            const int cp = ps - 4;
            // D_pre: uniform-address global loads -> SGPRs (no VGPR pressure)
            const float2* __restrict__ dp = gtab + WS_DPRE + cp * 16;
            #pragma unroll
            for (int i = 0; i < 16; ++i) a[i] = cmul(a[i], dp[i]);
            // real RY stages
            const float2* __restrict__ cst = gtab + WS_CS + cp * 4;
            #pragma unroll
            for (int q = 0; q < 4; ++q) {
                if (q < nw) {
                    const float2 csq = cst[q];
                    const float c = csq.x, s = csq.y;
                    #pragma unroll
                    for (int i = 0; i < 16; ++i) {
                        if (!((i >> q) & 1)) {
                            const int i1 = i | (1 << q);
                            float2 a0 = a[i], a1 = a[i1];
                            float2 n0, n1;
                            n0.x = c * a0.x - s * a1.x;
                            n0.y = c * a0.y - s * a1.y;
                            n1.x = s * a0.x + c * a1.x;
                            n1.y = s * a0.y + c * a1.y;
                            a[i] = n0; a[i1] = n1;
                        }
                    }
                }
            }
            // D_post (layer 1 only)
            if (ps < 8) {
                const float2* __restrict__ dq = gtab + WS_DPOST + cp * 16;
                #pragma unroll
                for (int i = 0; i < 16; ++i) a[i] = cmul(a[i], dq[i]);
            }
        }

        #pragma unroll
        for (int i = 0; i < 16; ++i)
            *(float2*)(sb + (rb ^ c8[i])) = a[i];
    }

    __syncthreads();

    // ---- measurement: logit = sum_p |amp_p|^2 * ws(p) + bias (addr space) ----
    float A[16];
    #pragma unroll
    for (int k = 0; k < 16; ++k) A[k] = 0.f;
    #pragma unroll
    for (int w = 0; w < NQ; ++w) {
        const unsigned msw = (unsigned)P.ms[w];
        float v = wl[w];
        unsigned s0 = __popc((unsigned)tid & (msw & 1023u)) & 1u;
        float vs = s0 ? -v : v;
        const unsigned hk = msw >> 10;      // wave-uniform 4-bit pattern
        #pragma unroll
        for (int k = 0; k < 16; ++k) {
            bool neg = (__popc((unsigned)k & hk) & 1) != 0;
            A[k] += neg ? -vs : vs;
        }
    }

    float acc = 0.f;
    #pragma unroll
    for (int k = 0; k < 16; ++k) {
        float2 a = st[k * BT + tid];
        acc = fmaf(fmaf(a.x, a.x, a.y * a.y), A[k], acc);
    }

    #pragma unroll
    for (int off = 32; off > 0; off >>= 1) acc += __shfl_down(acc, off, 64);
    int lane = tid & 63, wid = tid >> 6;
    if (lane == 0) red[wid] = acc;
    __syncthreads();
    if (tid == 0) {
        float s = 0.f;
        #pragma unroll
        for (int i = 0; i < NWAVES; ++i) s += red[i];
        out[b] = s + bl[0];
    }
}

// ---- host-side GF(2) helpers ----
struct GF2Basis {
    unsigned piv[NQ];
    GF2Basis() { for (int i = 0; i < NQ; ++i) piv[i] = 0; }
    bool insert(unsigned v) {            // true iff rank increased
        for (int bb = NQ - 1; bb >= 0; --bb) {
            if (!((v >> bb) & 1)) continue;
            if (piv[bb]) v ^= piv[bb];
            else { piv[bb] = v; return true; }
        }
        return false;
    }
};

static inline int par16(unsigned v) { return __builtin_parity(v); }
static inline unsigned lcg_next(unsigned& s) { s = s * 1664525u + 1013904223u; return s >> 8; }

static unsigned gf_apply(const unsigned* C, unsigned v) {
    unsigned r = 0;
    while (v) { int j = __builtin_ctz(v); v &= v - 1; r ^= C[j]; }
    return r;
}

// C = columns of sigma; on success Ci = columns of sigma^{-1}
static bool gf_invert(const unsigned* C, unsigned* Ci) {
    unsigned rows[NQ], irows[NQ];
    for (int i = 0; i < NQ; ++i) {
        unsigned r = 0;
        for (int j = 0; j < NQ; ++j) r |= ((C[j] >> i) & 1u) << j;
        rows[i] = r; irows[i] = 1u << i;
    }
    for (int c = 0; c < NQ; ++c) {
        int p = -1;
        for (int r = c; r < NQ; ++r) if ((rows[r] >> c) & 1u) { p = r; break; }
        if (p < 0) return false;
        unsigned t = rows[p]; rows[p] = rows[c]; rows[c] = t;
        t = irows[p]; irows[p] = irows[c]; irows[c] = t;
        for (int r = 0; r < NQ; ++r)
            if (r != c && ((rows[r] >> c) & 1u)) { rows[r] ^= rows[c]; irows[r] ^= irows[c]; }
    }
    for (int j = 0; j < NQ; ++j) {
        unsigned col = 0;
        for (int i = 0; i < NQ; ++i) col |= ((irows[i] >> j) & 1u) << i;
        Ci[j] = col;
    }
    return true;
}

extern "C" void kernel_launch(void* const* d_in, const int* in_sizes, int n_in,
                              void* d_out, int out_size, void* d_ws, size_t ws_size,
                              hipStream_t stream) {
    const float* x  = (const float*)d_in[0];   // (B, 14)
    const float* qw = (const float*)d_in[1];   // (3, 14, 3)
    const float* wl = (const float*)d_in[2];   // (1, 14)
    const float* bl = (const float*)d_in[3];   // (1,)
    float* out = (float*)d_out;                // (B, 1)

    const int B = in_sizes[0] / NQ;

    // ---- build passes in INDEX space (lazy-CNOT GF(2) bookkeeping) ----
    // s[w] = selector row of Q, m[w] = column of Q^-1; par(s_i & m_j)=delta_ij.
    struct Raw { unsigned rv[10], cmb[16]; } raw[NPASS];
    unsigned s[NQ], m[NQ], msIdx[NQ];
    for (int w = 0; w < NQ; ++w) s[w] = m[w] = 1u << (NQ - 1 - w); // wire 0 = MSB

    int ps = 0;
    for (int l = 0; l < NL; ++l) {
        for (int g0 = 0; g0 < NQ; g0 += 4) {
            int nw = (NQ - g0) < 4 ? (NQ - g0) : 4;
            unsigned mm[4], ss[4];
            GF2Basis gf;
            for (int i = 0; i < nw; ++i) { mm[i] = m[g0 + i]; ss[i] = s[g0 + i]; gf.insert(mm[i]); }
            // pad to 4 independent masks; normalize pads so they don't flip
            // the real wires' logical bits
            for (int i = nw; i < 4; ++i) {
                unsigned cand = 0;
                for (int t = 0; t < NQ; ++t)
                    if (gf.insert(1u << t)) { cand = 1u << t; break; }
                for (int j = 0; j < nw; ++j)
                    if (par16(cand & ss[j])) cand ^= mm[j];
                mm[i] = cand; ss[i] = 0;
            }
            // complement basis (10 vecs), normalized to zero logical bits
            int nR = 0;
            for (int t = 0; t < NQ && nR < 10; ++t) {
                if (gf.insert(1u << t)) {
                    unsigned v = 1u << t;
                    for (int j = 0; j < nw; ++j)
                        if (par16(v & ss[j])) v ^= mm[j];
                    raw[ps].rv[nR++] = v;
                }
            }
            for (int idx = 0; idx < 16; ++idx) {
                unsigned c = 0;
                for (int q = 0; q < 4; ++q) if ((idx >> q) & 1) c ^= mm[q];
                raw[ps].cmb[idx] = c;
            }
            ++ps;
        }
        int r = (l % (NQ - 1)) + 1;        // PennyLane ranges: 1,2,3
        for (int w = 0; w < NQ; ++w) {     // CNOT ring: control w, target (w+r)%NQ
            int c = w, t = (w + r) % NQ;
            s[t] ^= s[c];
            m[c] ^= m[t];
        }
    }
    for (int w = 0; w < NQ; ++w) msIdx[w] = s[w];

    // ---- choose layout sigma: every pass's rep space must project with
    // rank 4 onto the bank-pair bits (addr mod 16) ----
    unsigned Cm[NQ], Ci[NQ];
    unsigned seed = 0x9E3779B9u;
    bool found = false;
    for (int tries = 0; tries < 5000 && !found; ++tries) {
        for (int j = 0; j < NQ; ++j) Cm[j] = lcg_next(seed) & (NSTATE - 1);
        if (!gf_invert(Cm, Ci)) continue;
        found = true;
        for (int p = 0; p < NPASS && found; ++p) {
            unsigned piv[4] = {0, 0, 0, 0}; int np = 0;
            for (int i = 0; i < 10; ++i) {
                unsigned w2 = gf_apply(Cm, raw[p].rv[i]);
                for (int bb = 0; bb < 4; ++bb)
                    if (((w2 >> bb) & 1u) && piv[bb]) w2 ^= piv[bb];
                if ((w2 & 15u) && np < 4) { piv[__builtin_ctz(w2 & 15u)] = w2; ++np; }
            }
            if (np < 4) found = false;
        }
    }
    if (!found) {  // fallback: identity layout (correct, just slower)
        for (int j = 0; j < NQ; ++j) Cm[j] = 1u << j;
        gf_invert(Cm, Ci);
    }

    // ---- emit device params in ADDRESS space ----
    SimParams P;
    for (int p = 0; p < NPASS; ++p) {
        unsigned u[10];
        for (int i = 0; i < 10; ++i) u[i] = gf_apply(Cm, raw[p].rv[i]);
        // order: 4 bank-pivot vectors first (they cover lane bits 0..3)
        unsigned piv[4] = {0, 0, 0, 0};
        int ord[10], np = 0, rest[10], nrest = 0;
        for (int i = 0; i < 10; ++i) {
            unsigned w2 = u[i];
            for (int bb = 0; bb < 4; ++bb)
                if (((w2 >> bb) & 1u) && piv[bb]) w2 ^= piv[bb];
            if ((w2 & 15u) && np < 4) { piv[__builtin_ctz(w2 & 15u)] = w2; ord[np++] = i; }
            else rest[nrest++] = i;
        }
        int kk = 0;
        for (int i = 0; i < np; ++i) P.pass[p].R[kk++] = (unsigned short)u[ord[i]];
        for (int i = 0; i < nrest; ++i) P.pass[p].R[kk++] = (unsigned short)u[rest[i]];
        for (int idx = 0; idx < 16; ++idx)
            P.pass[p].cmb[idx] = (unsigned short)gf_apply(Cm, raw[p].cmb[idx]);
    }
    // measurement masks: par(sigma^{-1}(t) & ms) = par(t & sigma^{-T} ms)
    for (int w = 0; w < NQ; ++w) {
        unsigned msp = 0;
        for (int i = 0; i < NQ; ++i)
            msp |= (unsigned)(par16(Ci[i] & msIdx[w]) & 1) << i;
        P.ms[w] = (unsigned short)msp;
    }

    float2* gtab = (float2*)d_ws;
    prep_kernel<<<dim3(1), dim3(256), 0, stream>>>(qw, gtab);
    qsim_kernel<<<dim3(B), dim3(BT), 0, stream>>>(x, qw, wl, bl, out, gtab, P);
}